// Round 2
// baseline (1378.355 us; speedup 1.0000x reference)
//
#include <hip/hip_runtime.h>
#include <hip/hip_bf16.h>

using bf16 = __hip_bfloat16;

#define NN 50000
#define EE 800000
#define DD 128
#define HH 8
#define CC 16
#define EDD 32
#define DF 512

__device__ __forceinline__ float b2f(bf16 v) { return __bfloat162float(v); }

// ---- edge_index width detection: int64 has zero high-words (values < 50000)
__global__ void k_detect(const int* __restrict__ ei, int* __restrict__ flag)
{
    if (threadIdx.x == 0 && blockIdx.x == 0) {
        int all0 = 1;
        for (int i = 0; i < 16; ++i) all0 &= (ei[2 * i + 1] == 0);
        flag[0] = all0;  // 1 => int64 layout, 0 => int32
    }
}

__device__ __forceinline__ int load_src(const int* ei, int is64, int i)
{
    int s = is64 ? ei[2 * i] : ei[i];
    return (s < 0) ? 0 : (s >= NN ? NN - 1 : s);
}
__device__ __forceinline__ int load_dst(const int* ei, int is64, int i)
{
    int d = is64 ? ei[2 * EE + 2 * i] : ei[EE + i];
    return (d < 0) ? 0 : (d >= NN ? NN - 1 : d);
}

// ---------------- projections: q,k,v (bf16) and skip (fp32) ----------------
__global__ __launch_bounds__(512) void k_proj(
    const float* __restrict__ x,
    const float* __restrict__ Wq, const float* __restrict__ bq,
    const float* __restrict__ Wk, const float* __restrict__ bk,
    const float* __restrict__ Wv, const float* __restrict__ bv,
    const float* __restrict__ Wsk, const float* __restrict__ bsk,
    bf16* __restrict__ qb, bf16* __restrict__ kb, bf16* __restrict__ vb,
    float* __restrict__ skipb)
{
    __shared__ __align__(16) float xs[32][132];
    const int t = threadIdx.x;
    const int n0 = blockIdx.x * 32;
    for (int idx = t; idx < 32 * 128; idx += 512) {
        int i = idx >> 7, kc = idx & 127;
        int n = n0 + i;
        xs[i][kc] = (n < NN) ? x[n * 128 + kc] : 0.f;
    }
    __syncthreads();
    const int mi = t >> 7, jj = t & 127;
    const float* W = (mi == 0) ? Wq : (mi == 1) ? Wk : (mi == 2) ? Wv : Wsk;
    float acc[32];
#pragma unroll
    for (int i = 0; i < 32; i++) acc[i] = 0.f;
    for (int k = 0; k < 128; k += 4) {
        float w0 = W[(k + 0) * 128 + jj];
        float w1 = W[(k + 1) * 128 + jj];
        float w2 = W[(k + 2) * 128 + jj];
        float w3 = W[(k + 3) * 128 + jj];
#pragma unroll
        for (int i = 0; i < 32; i++) {
            float4 xv = *reinterpret_cast<const float4*>(&xs[i][k]);
            acc[i] = fmaf(xv.x, w0, fmaf(xv.y, w1, fmaf(xv.z, w2, fmaf(xv.w, w3, acc[i]))));
        }
    }
    float bias = ((mi == 0) ? bq : (mi == 1) ? bk : (mi == 2) ? bv : bsk)[jj];
#pragma unroll 1
    for (int i = 0; i < 32; i++) {
        int n = n0 + i;
        if (n >= NN) break;
        float v = acc[i] + bias;
        if (mi == 0)      qb[n * 128 + jj] = __float2bfloat16(v);
        else if (mi == 1) kb[n * 128 + jj] = __float2bfloat16(v);
        else if (mi == 2) vb[n * 128 + jj] = __float2bfloat16(v);
        else              skipb[n * 128 + jj] = v;
    }
}

// ---------------- CSR build ----------------
__global__ void k_hist(const int* __restrict__ ei, const int* __restrict__ flag,
                       int* __restrict__ deg)
{
    int i = blockIdx.x * 256 + threadIdx.x;
    if (i >= EE) return;
    atomicAdd(&deg[load_dst(ei, flag[0], i)], 1);
}

__global__ __launch_bounds__(1024) void k_scan(const int* __restrict__ deg,
                                               int* __restrict__ rowstart)
{
    __shared__ int s[1024];
    const int t = threadIdx.x;
    const int CH = 49;  // 1024*49 >= 50000
    int base = t * CH;
    int sum = 0;
    for (int i = 0; i < CH; i++) {
        int idx = base + i;
        if (idx < NN) sum += deg[idx];
    }
    s[t] = sum;
    __syncthreads();
    int own = sum;
    for (int off = 1; off < 1024; off <<= 1) {
        int v = (t >= off) ? s[t - off] : 0;
        __syncthreads();
        s[t] += v;
        __syncthreads();
    }
    int run = s[t] - own;  // exclusive prefix
    for (int i = 0; i < CH; i++) {
        int idx = base + i;
        if (idx < NN) {
            rowstart[idx] = run;
            run += deg[idx];
        }
    }
    if (t == 0) rowstart[NN] = EE;
}

__global__ void k_scatter(const int* __restrict__ ei, const int* __restrict__ flag,
                          const int* __restrict__ rowstart,
                          int* __restrict__ cursor, int* __restrict__ srcs,
                          int* __restrict__ eids)
{
    int i = blockIdx.x * 256 + threadIdx.x;
    if (i >= EE) return;
    int is64 = flag[0];
    int d = load_dst(ei, is64, i);
    int pos = rowstart[d] + atomicAdd(&cursor[d], 1);
    srcs[pos] = load_src(ei, is64, i);
    eids[pos] = i;
}

// ---------------- attention (online softmax per node) + LN1 ----------------
__global__ __launch_bounds__(128) void k_attn(
    const float* __restrict__ x, const float* __restrict__ edge_attr,
    const float* __restrict__ We,
    const bf16* __restrict__ qb, const bf16* __restrict__ kb,
    const bf16* __restrict__ vb, const float* __restrict__ skipb,
    const int* __restrict__ rowstart, const int* __restrict__ srcs,
    const int* __restrict__ eids,
    const float* __restrict__ ln1g, const float* __restrict__ ln1b,
    float* __restrict__ hb)
{
    const int n = blockIdx.x;
    const int t = threadIdx.x;     // channel 0..127; head = t>>4
    const int lane = t & 63;
    float we[32];
#pragma unroll
    for (int d = 0; d < 32; ++d) we[d] = We[d * 128 + t];
    float q_t = b2f(qb[n * 128 + t]);
    const int eoff = rowstart[n], eend = rowstart[n + 1];
    float m = -1e30f, l = 0.f, acc = 0.f;
    for (int p = eoff; p < eend; ++p) {
        int src = srcs[p];
        int eid = eids[p];
        float eav = edge_attr[eid * 32 + (lane & 31)];
        float e_t = 0.f;
#pragma unroll
        for (int d = 0; d < 32; ++d) e_t = fmaf(we[d], __shfl(eav, d), e_t);
        float ke = b2f(kb[src * 128 + t]) + e_t;
        float prod = q_t * ke;
        prod += __shfl_xor(prod, 1);
        prod += __shfl_xor(prod, 2);
        prod += __shfl_xor(prod, 4);
        prod += __shfl_xor(prod, 8);
        float alpha = prod * 0.25f;  // 1/sqrt(16)
        float mn = fmaxf(m, alpha);
        float sc = __expf(m - mn);
        float pw = __expf(alpha - mn);
        l = l * sc + pw;
        float ve = b2f(vb[src * 128 + t]) + e_t;
        acc = acc * sc + ve * pw;
        m = mn;
    }
    float attn = acc / (l + 1e-16f);
    float pre = x[n * 128 + t] + attn + skipb[n * 128 + t];
    // LayerNorm over 128 channels
    float s1 = pre, s2 = pre * pre;
#pragma unroll
    for (int off = 1; off < 64; off <<= 1) {
        s1 += __shfl_xor(s1, off);
        s2 += __shfl_xor(s2, off);
    }
    __shared__ float r1[2], r2[2];
    const int wid = t >> 6;
    if (lane == 0) { r1[wid] = s1; r2[wid] = s2; }
    __syncthreads();
    float mu = (r1[0] + r1[1]) * (1.f / 128.f);
    float ms = (r2[0] + r2[1]) * (1.f / 128.f);
    float var = ms - mu * mu;
    float inv = rsqrtf(var + 1e-5f);
    float h = (pre - mu) * inv * ln1g[t] + ln1b[t];
    hb[n * 128 + t] = h;
}

// ---------------- FFN + LN2 ----------------
__global__ __launch_bounds__(512) void k_ffn(
    const float* __restrict__ hb,
    const float* __restrict__ W1, const float* __restrict__ b1,
    const float* __restrict__ W2, const float* __restrict__ b2,
    const float* __restrict__ ln2g, const float* __restrict__ ln2b,
    float* __restrict__ out)
{
    __shared__ __align__(16) float hs[8][132];
    __shared__ __align__(16) float t1s[8][516];
    __shared__ __align__(16) float part[8 * 512];
    __shared__ float fs[8 * 128];
    __shared__ float r1[8], r2[8];
    const int t = threadIdx.x;
    const int n0 = blockIdx.x * 8;
    for (int idx = t; idx < 8 * 128; idx += 512) {
        int i = idx >> 7, k = idx & 127;
        hs[i][k] = hb[(n0 + i) * 128 + k];
    }
    __syncthreads();
    // GEMM1: t1 = relu(h @ W1 + b1), j = t in [0,512)
    {
        const int j = t;
        float acc[8];
#pragma unroll
        for (int i = 0; i < 8; i++) acc[i] = 0.f;
        for (int k = 0; k < 128; k += 4) {
            float w0 = W1[(k + 0) * 512 + j];
            float w1 = W1[(k + 1) * 512 + j];
            float w2 = W1[(k + 2) * 512 + j];
            float w3 = W1[(k + 3) * 512 + j];
#pragma unroll
            for (int i = 0; i < 8; i++) {
                float4 xv = *reinterpret_cast<const float4*>(&hs[i][k]);
                acc[i] = fmaf(xv.x, w0, fmaf(xv.y, w1, fmaf(xv.z, w2, fmaf(xv.w, w3, acc[i]))));
            }
        }
        float bias = b1[j];
#pragma unroll
        for (int i = 0; i < 8; i++) t1s[i][j] = fmaxf(acc[i] + bias, 0.f);
    }
    __syncthreads();
    // GEMM2 split-K: jj = t&127, kg = t>>7 covers k in [kg*128, kg*128+128)
    {
        const int jj = t & 127, kg = t >> 7;
        float acc[8];
#pragma unroll
        for (int i = 0; i < 8; i++) acc[i] = 0.f;
        const int kbase = kg * 128;
        for (int k = 0; k < 128; k += 4) {
            int k2 = kbase + k;
            float w0 = W2[(k2 + 0) * 128 + jj];
            float w1 = W2[(k2 + 1) * 128 + jj];
            float w2 = W2[(k2 + 2) * 128 + jj];
            float w3 = W2[(k2 + 3) * 128 + jj];
#pragma unroll
            for (int i = 0; i < 8; i++) {
                float4 xv = *reinterpret_cast<const float4*>(&t1s[i][k2]);
                acc[i] = fmaf(xv.x, w0, fmaf(xv.y, w1, fmaf(xv.z, w2, fmaf(xv.w, w3, acc[i]))));
            }
        }
#pragma unroll
        for (int i = 0; i < 8; i++) part[i * 512 + jj * 4 + kg] = acc[i];
    }
    __syncthreads();
    for (int idx = t; idx < 8 * 128; idx += 512) {
        int i = idx >> 7, jj = idx & 127;
        const float* p4 = &part[i * 512 + jj * 4];
        fs[idx] = p4[0] + p4[1] + p4[2] + p4[3] + b2[jj];
    }
    __syncthreads();
    // LN2 + output: 4 nodes in parallel per pass, 2 passes
    const int jj = t & 127;
    const int slot = t >> 7;  // 0..3
    const int wid = t >> 6;   // 0..7
    const int lane = t & 63;
    for (int g = 0; g < 2; ++g) {
        int i = g * 4 + slot;
        float pre = hs[i][jj] + fs[i * 128 + jj];
        float s1 = pre, s2 = pre * pre;
#pragma unroll
        for (int off = 1; off < 64; off <<= 1) {
            s1 += __shfl_xor(s1, off);
            s2 += __shfl_xor(s2, off);
        }
        if (lane == 0) { r1[wid] = s1; r2[wid] = s2; }
        __syncthreads();
        int wp = slot * 2;
        float mu = (r1[wp] + r1[wp + 1]) * (1.f / 128.f);
        float ms = (r2[wp] + r2[wp + 1]) * (1.f / 128.f);
        float var = ms - mu * mu;
        float inv = rsqrtf(var + 1e-5f);
        float o = (pre - mu) * inv * ln2g[jj] + ln2b[jj];
        out[(n0 + i) * 128 + jj] = o;
        __syncthreads();
    }
}

extern "C" void kernel_launch(void* const* d_in, const int* in_sizes, int n_in,
                              void* d_out, int out_size, void* d_ws, size_t ws_size,
                              hipStream_t stream)
{
    const float* x    = (const float*)d_in[0];
    const int*   ei   = (const int*)d_in[1];
    const float* ea   = (const float*)d_in[2];
    const float* Wq   = (const float*)d_in[3];
    const float* bq   = (const float*)d_in[4];
    const float* Wk   = (const float*)d_in[5];
    const float* bk   = (const float*)d_in[6];
    const float* Wv   = (const float*)d_in[7];
    const float* bv   = (const float*)d_in[8];
    const float* We   = (const float*)d_in[9];
    const float* Wsk  = (const float*)d_in[10];
    const float* bsk  = (const float*)d_in[11];
    const float* ln1g = (const float*)d_in[12];
    const float* ln1b = (const float*)d_in[13];
    const float* W1   = (const float*)d_in[14];
    const float* b1   = (const float*)d_in[15];
    const float* W2   = (const float*)d_in[16];
    const float* b2   = (const float*)d_in[17];
    const float* ln2g = (const float*)d_in[18];
    const float* ln2b = (const float*)d_in[19];

    char* ws = (char*)d_ws;
    size_t off = 0;
    auto alloc = [&](size_t bytes) -> void* {
        void* p = ws + off;
        off += (bytes + 255) & ~(size_t)255;
        return p;
    };
    int*   flag     = (int*)alloc(256);
    int*   deg      = (int*)alloc((size_t)NN * 4);
    int*   cursor   = (int*)alloc((size_t)NN * 4);
    int*   rowstart = (int*)alloc((size_t)(NN + 1) * 4);
    int*   srcs     = (int*)alloc((size_t)EE * 4);
    int*   eids     = (int*)alloc((size_t)EE * 4);
    bf16*  qb       = (bf16*)alloc((size_t)NN * 128 * 2);
    bf16*  kb       = (bf16*)alloc((size_t)NN * 128 * 2);
    bf16*  vb       = (bf16*)alloc((size_t)NN * 128 * 2);
    float* skipb    = (float*)alloc((size_t)NN * 128 * 4);
    float* hb       = (float*)alloc((size_t)NN * 128 * 4);

    hipMemsetAsync(deg, 0, (size_t)NN * 4, stream);
    hipMemsetAsync(cursor, 0, (size_t)NN * 4, stream);

    k_detect<<<1, 64, 0, stream>>>(ei, flag);
    k_hist<<<(EE + 255) / 256, 256, 0, stream>>>(ei, flag, deg);
    k_proj<<<(NN + 31) / 32, 512, 0, stream>>>(x, Wq, bq, Wk, bk, Wv, bv, Wsk, bsk,
                                               qb, kb, vb, skipb);
    k_scan<<<1, 1024, 0, stream>>>(deg, rowstart);
    k_scatter<<<(EE + 255) / 256, 256, 0, stream>>>(ei, flag, rowstart, cursor, srcs, eids);
    k_attn<<<NN, 128, 0, stream>>>(x, ea, We, qb, kb, vb, skipb,
                                   rowstart, srcs, eids, ln1g, ln1b, hb);
    k_ffn<<<NN / 8, 512, 0, stream>>>(hb, W1, b1, W2, b2, ln2g, ln2b, (float*)d_out);
}

// Round 3
// 1075.412 us; speedup vs baseline: 1.2817x; 1.2817x over previous
//
#include <hip/hip_runtime.h>
#include <hip/hip_bf16.h>

using bf16 = __hip_bfloat16;
typedef __attribute__((ext_vector_type(8))) short short8;
typedef __attribute__((ext_vector_type(4))) float floatx4;

#define NN 50000
#define EE 800000
#define DD 128
#define HH 8
#define CC 16
#define EDD 32
#define DF 512

__device__ __forceinline__ float b2f(bf16 v) { return __bfloat162float(v); }
__device__ __forceinline__ short f2bs(float v) {
    bf16 h = __float2bfloat16(v);
    return *reinterpret_cast<short*>(&h);
}

// ---- edge_index width detection: int64 has zero high-words (values < 50000)
__global__ void k_detect(const int* __restrict__ ei, int* __restrict__ flag)
{
    if (threadIdx.x == 0 && blockIdx.x == 0) {
        int all0 = 1;
        for (int i = 0; i < 16; ++i) all0 &= (ei[2 * i + 1] == 0);
        flag[0] = all0;  // 1 => int64 layout, 0 => int32
    }
}

__device__ __forceinline__ int load_src(const int* ei, int is64, int i)
{
    int s = is64 ? ei[2 * i] : ei[i];
    return (s < 0) ? 0 : (s >= NN ? NN - 1 : s);
}
__device__ __forceinline__ int load_dst(const int* ei, int is64, int i)
{
    int d = is64 ? ei[2 * EE + 2 * i] : ei[EE + i];
    return (d < 0) ? 0 : (d >= NN ? NN - 1 : d);
}

// ---------------- projections: q,k,v (bf16) and skip (fp32) ----------------
__global__ __launch_bounds__(512) void k_proj(
    const float* __restrict__ x,
    const float* __restrict__ Wq, const float* __restrict__ bq,
    const float* __restrict__ Wk, const float* __restrict__ bk,
    const float* __restrict__ Wv, const float* __restrict__ bv,
    const float* __restrict__ Wsk, const float* __restrict__ bsk,
    bf16* __restrict__ qb, bf16* __restrict__ kb, bf16* __restrict__ vb,
    float* __restrict__ skipb)
{
    __shared__ __align__(16) float xs[32][132];
    const int t = threadIdx.x;
    const int n0 = blockIdx.x * 32;
    for (int idx = t; idx < 32 * 128; idx += 512) {
        int i = idx >> 7, kc = idx & 127;
        int n = n0 + i;
        xs[i][kc] = (n < NN) ? x[n * 128 + kc] : 0.f;
    }
    __syncthreads();
    const int mi = t >> 7, jj = t & 127;
    const float* W = (mi == 0) ? Wq : (mi == 1) ? Wk : (mi == 2) ? Wv : Wsk;
    float acc[32];
#pragma unroll
    for (int i = 0; i < 32; i++) acc[i] = 0.f;
    for (int k = 0; k < 128; k += 4) {
        float w0 = W[(k + 0) * 128 + jj];
        float w1 = W[(k + 1) * 128 + jj];
        float w2 = W[(k + 2) * 128 + jj];
        float w3 = W[(k + 3) * 128 + jj];
#pragma unroll
        for (int i = 0; i < 32; i++) {
            float4 xv = *reinterpret_cast<const float4*>(&xs[i][k]);
            acc[i] = fmaf(xv.x, w0, fmaf(xv.y, w1, fmaf(xv.z, w2, fmaf(xv.w, w3, acc[i]))));
        }
    }
    float bias = ((mi == 0) ? bq : (mi == 1) ? bk : (mi == 2) ? bv : bsk)[jj];
#pragma unroll 1
    for (int i = 0; i < 32; i++) {
        int n = n0 + i;
        if (n >= NN) break;
        float v = acc[i] + bias;
        if (mi == 0)      qb[n * 128 + jj] = __float2bfloat16(v);
        else if (mi == 1) kb[n * 128 + jj] = __float2bfloat16(v);
        else if (mi == 2) vb[n * 128 + jj] = __float2bfloat16(v);
        else              skipb[n * 128 + jj] = v;
    }
}

// ---------------- CSR build ----------------
__global__ void k_hist(const int* __restrict__ ei, const int* __restrict__ flag,
                       int* __restrict__ deg)
{
    int i = blockIdx.x * 256 + threadIdx.x;
    if (i >= EE) return;
    atomicAdd(&deg[load_dst(ei, flag[0], i)], 1);
}

__global__ __launch_bounds__(1024) void k_scan(const int* __restrict__ deg,
                                               int* __restrict__ rowstart)
{
    __shared__ int s[1024];
    const int t = threadIdx.x;
    const int CH = 49;  // 1024*49 >= 50000
    int base = t * CH;
    int sum = 0;
    for (int i = 0; i < CH; i++) {
        int idx = base + i;
        if (idx < NN) sum += deg[idx];
    }
    s[t] = sum;
    __syncthreads();
    int own = sum;
    for (int off = 1; off < 1024; off <<= 1) {
        int v = (t >= off) ? s[t - off] : 0;
        __syncthreads();
        s[t] += v;
        __syncthreads();
    }
    int run = s[t] - own;  // exclusive prefix
    for (int i = 0; i < CH; i++) {
        int idx = base + i;
        if (idx < NN) {
            rowstart[idx] = run;
            run += deg[idx];
        }
    }
    if (t == 0) rowstart[NN] = EE;
}

__global__ void k_scatter(const int* __restrict__ ei, const int* __restrict__ flag,
                          const int* __restrict__ rowstart,
                          int* __restrict__ cursor, int* __restrict__ srcs,
                          int* __restrict__ eids)
{
    int i = blockIdx.x * 256 + threadIdx.x;
    if (i >= EE) return;
    int is64 = flag[0];
    int d = load_dst(ei, is64, i);
    int pos = rowstart[d] + atomicAdd(&cursor[d], 1);
    srcs[pos] = load_src(ei, is64, i);
    eids[pos] = i;
}

// ---------------- e = edge_attr @ We, CSR-ordered output (MFMA) ----------------
// block = 256 threads = 4 waves; wave handles 16 CSR positions; K=32 = one MFMA.
__global__ __launch_bounds__(256) void k_egemm(
    const float* __restrict__ edge_attr, const float* __restrict__ We,
    const int* __restrict__ eids, bf16* __restrict__ eb)
{
    __shared__ __align__(16) short lds[4][16][136];
    const int t = threadIdx.x;
    const int wave = t >> 6, lane = t & 63;
    const int quad = lane >> 4, m = lane & 15;
    const int p0 = blockIdx.x * 64 + wave * 16;

    // B frags: We[k][n] with k = quad*8+j, n = tile*16 + m
    short8 Bf[8];
#pragma unroll
    for (int tile = 0; tile < 8; ++tile) {
#pragma unroll
        for (int j = 0; j < 8; ++j)
            Bf[tile][j] = f2bs(We[(quad * 8 + j) * 128 + tile * 16 + m]);
    }
    // A frag: row m (CSR position p0+m), k = quad*8+j
    int eid = eids[p0 + m];
    const float* arow = edge_attr + (size_t)eid * 32 + quad * 8;
    float4 a0 = *reinterpret_cast<const float4*>(arow);
    float4 a1 = *reinterpret_cast<const float4*>(arow + 4);
    short8 Af;
    Af[0] = f2bs(a0.x); Af[1] = f2bs(a0.y); Af[2] = f2bs(a0.z); Af[3] = f2bs(a0.w);
    Af[4] = f2bs(a1.x); Af[5] = f2bs(a1.y); Af[6] = f2bs(a1.z); Af[7] = f2bs(a1.w);

#pragma unroll
    for (int tile = 0; tile < 8; ++tile) {
        floatx4 C = {0.f, 0.f, 0.f, 0.f};
        C = __builtin_amdgcn_mfma_f32_16x16x32_bf16(Af, Bf[tile], C, 0, 0, 0);
        // C layout: col = lane&15 (within tile), row = quad*4 + r
#pragma unroll
        for (int r = 0; r < 4; ++r)
            lds[wave][quad * 4 + r][tile * 16 + m] = f2bs(C[r]);
    }
    __syncthreads();
    // cooperative vector store: 16 rows x 256 B per wave
#pragma unroll
    for (int pass = 0; pass < 4; ++pass) {
        int row = pass * 4 + quad;
        float4 vdat = *reinterpret_cast<const float4*>(&lds[wave][row][m * 8]);
        *reinterpret_cast<float4*>(&eb[(size_t)(p0 + row) * 128 + m * 8]) = vdat;
    }
}

// -------- attention (streaming e, online softmax, 2-wide pipeline) + LN1 --------
__global__ __launch_bounds__(128) void k_attn(
    const float* __restrict__ x,
    const bf16* __restrict__ qb, const bf16* __restrict__ kb,
    const bf16* __restrict__ vb, const float* __restrict__ skipb,
    const bf16* __restrict__ eb,
    const int* __restrict__ rowstart, const int* __restrict__ srcs,
    const float* __restrict__ ln1g, const float* __restrict__ ln1b,
    float* __restrict__ hb)
{
    const int n = blockIdx.x;
    const int t = threadIdx.x;     // channel 0..127
    const int lane = t & 63;
    float q_t = b2f(qb[n * 128 + t]);
    const int eoff = rowstart[n], eend = rowstart[n + 1];
    float m = -1e30f, l = 0.f, acc = 0.f;
    for (int p = eoff; p < eend; p += 2) {
        const bool has1 = (p + 1 < eend);
        int s0 = srcs[p];
        int s1 = has1 ? srcs[p + 1] : s0;
        int p1i = has1 ? p + 1 : p;
        float e0 = b2f(eb[(size_t)p * 128 + t]);
        float e1 = b2f(eb[(size_t)p1i * 128 + t]);
        float k0 = b2f(kb[s0 * 128 + t]);
        float k1 = b2f(kb[s1 * 128 + t]);
        float v0 = b2f(vb[s0 * 128 + t]);
        float v1 = b2f(vb[s1 * 128 + t]);
        float pr0 = q_t * (k0 + e0);
        float pr1 = q_t * (k1 + e1);
        pr0 += __shfl_xor(pr0, 1); pr1 += __shfl_xor(pr1, 1);
        pr0 += __shfl_xor(pr0, 2); pr1 += __shfl_xor(pr1, 2);
        pr0 += __shfl_xor(pr0, 4); pr1 += __shfl_xor(pr1, 4);
        pr0 += __shfl_xor(pr0, 8); pr1 += __shfl_xor(pr1, 8);
        float a0 = pr0 * 0.25f;  // 1/sqrt(16)
        float a1 = pr1 * 0.25f;
        float m2, l2, acc2;
        if (has1) {
            m2 = fmaxf(a0, a1);
            float w0 = __expf(a0 - m2), w1 = __expf(a1 - m2);
            l2 = w0 + w1;
            acc2 = (v0 + e0) * w0 + (v1 + e1) * w1;
        } else {
            m2 = a0; l2 = 1.f; acc2 = v0 + e0;
        }
        float mn = fmaxf(m, m2);
        float sA = __expf(m - mn), sB = __expf(m2 - mn);
        l = l * sA + l2 * sB;
        acc = acc * sA + acc2 * sB;
        m = mn;
    }
    float attn = acc / (l + 1e-16f);
    float pre = x[n * 128 + t] + attn + skipb[n * 128 + t];
    float s1 = pre, s2 = pre * pre;
#pragma unroll
    for (int off = 1; off < 64; off <<= 1) {
        s1 += __shfl_xor(s1, off);
        s2 += __shfl_xor(s2, off);
    }
    __shared__ float r1[2], r2[2];
    const int wid = t >> 6;
    if (lane == 0) { r1[wid] = s1; r2[wid] = s2; }
    __syncthreads();
    float mu = (r1[0] + r1[1]) * (1.f / 128.f);
    float ms = (r2[0] + r2[1]) * (1.f / 128.f);
    float var = ms - mu * mu;
    float inv = rsqrtf(var + 1e-5f);
    float h = (pre - mu) * inv * ln1g[t] + ln1b[t];
    hb[n * 128 + t] = h;
}

// -------- fallback attention (recompute e in-loop) for small ws --------
__global__ __launch_bounds__(128) void k_attn_noeb(
    const float* __restrict__ x, const float* __restrict__ edge_attr,
    const float* __restrict__ We,
    const bf16* __restrict__ qb, const bf16* __restrict__ kb,
    const bf16* __restrict__ vb, const float* __restrict__ skipb,
    const int* __restrict__ rowstart, const int* __restrict__ srcs,
    const int* __restrict__ eids,
    const float* __restrict__ ln1g, const float* __restrict__ ln1b,
    float* __restrict__ hb)
{
    const int n = blockIdx.x;
    const int t = threadIdx.x;
    const int lane = t & 63;
    float we[32];
#pragma unroll
    for (int d = 0; d < 32; ++d) we[d] = We[d * 128 + t];
    float q_t = b2f(qb[n * 128 + t]);
    const int eoff = rowstart[n], eend = rowstart[n + 1];
    float m = -1e30f, l = 0.f, acc = 0.f;
    for (int p = eoff; p < eend; ++p) {
        int src = srcs[p];
        int eid = eids[p];
        float eav = edge_attr[eid * 32 + (lane & 31)];
        float e_t = 0.f;
#pragma unroll
        for (int d = 0; d < 32; ++d) e_t = fmaf(we[d], __shfl(eav, d), e_t);
        float ke = b2f(kb[src * 128 + t]) + e_t;
        float prod = q_t * ke;
        prod += __shfl_xor(prod, 1);
        prod += __shfl_xor(prod, 2);
        prod += __shfl_xor(prod, 4);
        prod += __shfl_xor(prod, 8);
        float alpha = prod * 0.25f;
        float mn = fmaxf(m, alpha);
        float sc = __expf(m - mn);
        float pw = __expf(alpha - mn);
        l = l * sc + pw;
        float ve = b2f(vb[src * 128 + t]) + e_t;
        acc = acc * sc + ve * pw;
        m = mn;
    }
    float attn = acc / (l + 1e-16f);
    float pre = x[n * 128 + t] + attn + skipb[n * 128 + t];
    float s1 = pre, s2 = pre * pre;
#pragma unroll
    for (int off = 1; off < 64; off <<= 1) {
        s1 += __shfl_xor(s1, off);
        s2 += __shfl_xor(s2, off);
    }
    __shared__ float r1[2], r2[2];
    const int wid = t >> 6;
    if (lane == 0) { r1[wid] = s1; r2[wid] = s2; }
    __syncthreads();
    float mu = (r1[0] + r1[1]) * (1.f / 128.f);
    float ms = (r2[0] + r2[1]) * (1.f / 128.f);
    float var = ms - mu * mu;
    float inv = rsqrtf(var + 1e-5f);
    float h = (pre - mu) * inv * ln1g[t] + ln1b[t];
    hb[n * 128 + t] = h;
}

// ---------------- FFN + LN2 ----------------
__global__ __launch_bounds__(512) void k_ffn(
    const float* __restrict__ hb,
    const float* __restrict__ W1, const float* __restrict__ b1,
    const float* __restrict__ W2, const float* __restrict__ b2,
    const float* __restrict__ ln2g, const float* __restrict__ ln2b,
    float* __restrict__ out)
{
    __shared__ __align__(16) float hs[8][132];
    __shared__ __align__(16) float t1s[8][516];
    __shared__ __align__(16) float part[8 * 512];
    __shared__ float fs[8 * 128];
    __shared__ float r1[8], r2[8];
    const int t = threadIdx.x;
    const int n0 = blockIdx.x * 8;
    for (int idx = t; idx < 8 * 128; idx += 512) {
        int i = idx >> 7, k = idx & 127;
        hs[i][k] = hb[(n0 + i) * 128 + k];
    }
    __syncthreads();
    {
        const int j = t;
        float acc[8];
#pragma unroll
        for (int i = 0; i < 8; i++) acc[i] = 0.f;
        for (int k = 0; k < 128; k += 4) {
            float w0 = W1[(k + 0) * 512 + j];
            float w1 = W1[(k + 1) * 512 + j];
            float w2 = W1[(k + 2) * 512 + j];
            float w3 = W1[(k + 3) * 512 + j];
#pragma unroll
            for (int i = 0; i < 8; i++) {
                float4 xv = *reinterpret_cast<const float4*>(&hs[i][k]);
                acc[i] = fmaf(xv.x, w0, fmaf(xv.y, w1, fmaf(xv.z, w2, fmaf(xv.w, w3, acc[i]))));
            }
        }
        float bias = b1[j];
#pragma unroll
        for (int i = 0; i < 8; i++) t1s[i][j] = fmaxf(acc[i] + bias, 0.f);
    }
    __syncthreads();
    {
        const int jj = t & 127, kg = t >> 7;
        float acc[8];
#pragma unroll
        for (int i = 0; i < 8; i++) acc[i] = 0.f;
        const int kbase = kg * 128;
        for (int k = 0; k < 128; k += 4) {
            int k2 = kbase + k;
            float w0 = W2[(k2 + 0) * 128 + jj];
            float w1 = W2[(k2 + 1) * 128 + jj];
            float w2 = W2[(k2 + 2) * 128 + jj];
            float w3 = W2[(k2 + 3) * 128 + jj];
#pragma unroll
            for (int i = 0; i < 8; i++) {
                float4 xv = *reinterpret_cast<const float4*>(&t1s[i][k2]);
                acc[i] = fmaf(xv.x, w0, fmaf(xv.y, w1, fmaf(xv.z, w2, fmaf(xv.w, w3, acc[i]))));
            }
        }
#pragma unroll
        for (int i = 0; i < 8; i++) part[i * 512 + jj * 4 + kg] = acc[i];
    }
    __syncthreads();
    for (int idx = t; idx < 8 * 128; idx += 512) {
        int i = idx >> 7, jj = idx & 127;
        const float* p4 = &part[i * 512 + jj * 4];
        fs[idx] = p4[0] + p4[1] + p4[2] + p4[3] + b2[jj];
    }
    __syncthreads();
    const int jj = t & 127;
    const int slot = t >> 7;
    const int wid = t >> 6;
    const int lane = t & 63;
    for (int g = 0; g < 2; ++g) {
        int i = g * 4 + slot;
        float pre = hs[i][jj] + fs[i * 128 + jj];
        float s1 = pre, s2 = pre * pre;
#pragma unroll
        for (int off = 1; off < 64; off <<= 1) {
            s1 += __shfl_xor(s1, off);
            s2 += __shfl_xor(s2, off);
        }
        if (lane == 0) { r1[wid] = s1; r2[wid] = s2; }
        __syncthreads();
        int wp = slot * 2;
        float mu = (r1[wp] + r1[wp + 1]) * (1.f / 128.f);
        float ms = (r2[wp] + r2[wp + 1]) * (1.f / 128.f);
        float var = ms - mu * mu;
        float inv = rsqrtf(var + 1e-5f);
        float o = (pre - mu) * inv * ln2g[jj] + ln2b[jj];
        out[(n0 + i) * 128 + jj] = o;
        __syncthreads();
    }
}

extern "C" void kernel_launch(void* const* d_in, const int* in_sizes, int n_in,
                              void* d_out, int out_size, void* d_ws, size_t ws_size,
                              hipStream_t stream)
{
    const float* x    = (const float*)d_in[0];
    const int*   ei   = (const int*)d_in[1];
    const float* ea   = (const float*)d_in[2];
    const float* Wq   = (const float*)d_in[3];
    const float* bq   = (const float*)d_in[4];
    const float* Wk   = (const float*)d_in[5];
    const float* bk   = (const float*)d_in[6];
    const float* Wv   = (const float*)d_in[7];
    const float* bv   = (const float*)d_in[8];
    const float* We   = (const float*)d_in[9];
    const float* Wsk  = (const float*)d_in[10];
    const float* bsk  = (const float*)d_in[11];
    const float* ln1g = (const float*)d_in[12];
    const float* ln1b = (const float*)d_in[13];
    const float* W1   = (const float*)d_in[14];
    const float* b1   = (const float*)d_in[15];
    const float* W2   = (const float*)d_in[16];
    const float* b2   = (const float*)d_in[17];
    const float* ln2g = (const float*)d_in[18];
    const float* ln2b = (const float*)d_in[19];

    char* ws = (char*)d_ws;
    size_t off = 0;
    auto alloc = [&](size_t bytes) -> void* {
        void* p = ws + off;
        off += (bytes + 255) & ~(size_t)255;
        return p;
    };
    int*   flag     = (int*)alloc(256);
    int*   deg      = (int*)alloc((size_t)NN * 4);
    int*   cursor   = (int*)alloc((size_t)NN * 4);
    int*   rowstart = (int*)alloc((size_t)(NN + 1) * 4);
    int*   srcs     = (int*)alloc((size_t)EE * 4);
    int*   eids     = (int*)alloc((size_t)EE * 4);
    bf16*  qb       = (bf16*)alloc((size_t)NN * 128 * 2);
    bf16*  kb       = (bf16*)alloc((size_t)NN * 128 * 2);
    bf16*  vb       = (bf16*)alloc((size_t)NN * 128 * 2);
    float* skipb    = (float*)alloc((size_t)NN * 128 * 4);
    float* hb       = (float*)alloc((size_t)NN * 128 * 4);
    bf16*  eb       = (bf16*)alloc((size_t)EE * 128 * 2);
    const bool use_eb = (off <= ws_size);

    hipMemsetAsync(deg, 0, (size_t)NN * 4, stream);
    hipMemsetAsync(cursor, 0, (size_t)NN * 4, stream);

    k_detect<<<1, 64, 0, stream>>>(ei, flag);
    k_hist<<<(EE + 255) / 256, 256, 0, stream>>>(ei, flag, deg);
    k_proj<<<(NN + 31) / 32, 512, 0, stream>>>(x, Wq, bq, Wk, bk, Wv, bv, Wsk, bsk,
                                               qb, kb, vb, skipb);
    k_scan<<<1, 1024, 0, stream>>>(deg, rowstart);
    k_scatter<<<(EE + 255) / 256, 256, 0, stream>>>(ei, flag, rowstart, cursor, srcs, eids);
    if (use_eb) {
        k_egemm<<<EE / 64, 256, 0, stream>>>(ea, We, eids, eb);
        k_attn<<<NN, 128, 0, stream>>>(x, qb, kb, vb, skipb, eb,
                                       rowstart, srcs, ln1g, ln1b, hb);
    } else {
        k_attn_noeb<<<NN, 128, 0, stream>>>(x, ea, We, qb, kb, vb, skipb,
                                            rowstart, srcs, eids, ln1g, ln1b, hb);
    }
    k_ffn<<<NN / 8, 512, 0, stream>>>(hb, W1, b1, W2, b2, ln2g, ln2b, (float*)d_out);
}

// Round 4
// 738.916 us; speedup vs baseline: 1.8654x; 1.4554x over previous
//
#include <hip/hip_runtime.h>
#include <hip/hip_bf16.h>

using bf16 = __hip_bfloat16;
typedef __attribute__((ext_vector_type(8))) short short8;
typedef __attribute__((ext_vector_type(4))) float floatx4;

#define NN 50000
#define EE 800000
#define DD 128
#define HH 8
#define CC 16
#define EDD 32
#define DF 512

__device__ __forceinline__ float b2f(bf16 v) { return __bfloat162float(v); }
__device__ __forceinline__ float bs2f(short s) {
    bf16 h = *reinterpret_cast<bf16*>(&s);
    return __bfloat162float(h);
}
__device__ __forceinline__ short f2bs(float v) {
    bf16 h = __float2bfloat16(v);
    return *reinterpret_cast<short*>(&h);
}

// ---- edge_index width detection: int64 has zero high-words (values < 50000)
__global__ void k_detect(const int* __restrict__ ei, int* __restrict__ flag)
{
    if (threadIdx.x == 0 && blockIdx.x == 0) {
        int all0 = 1;
        for (int i = 0; i < 16; ++i) all0 &= (ei[2 * i + 1] == 0);
        flag[0] = all0;  // 1 => int64 layout, 0 => int32
    }
}

__device__ __forceinline__ int load_src(const int* ei, int is64, int i)
{
    int s = is64 ? ei[2 * i] : ei[i];
    return (s < 0) ? 0 : (s >= NN ? NN - 1 : s);
}
__device__ __forceinline__ int load_dst(const int* ei, int is64, int i)
{
    int d = is64 ? ei[2 * EE + 2 * i] : ei[EE + i];
    return (d < 0) ? 0 : (d >= NN ? NN - 1 : d);
}

// ---- pack fp32 weight [K][N] into per-lane MFMA B-frag layout (bf16) ----
// frag (ntile,kstep): 64 lanes x 8 bf16, lane=(quad,m): B[k=kstep*32+quad*8+j][n=ntile*16+m]
__global__ void k_pack(const float* __restrict__ W, bf16* __restrict__ out,
                       int ksteps, int N, int total)
{
    int idx = blockIdx.x * 256 + threadIdx.x;
    if (idx >= total) return;
    int j = idx & 7, lane = (idx >> 3) & 63, rest = idx >> 9;
    int kstep = rest % ksteps, ntile = rest / ksteps;
    int quad = lane >> 4, m = lane & 15;
    int k = kstep * 32 + quad * 8 + j;
    int n = ntile * 16 + m;
    out[idx] = __float2bfloat16(W[(size_t)k * N + n]);
}

// ---------------- projections via MFMA: q,k,v,skip (all bf16) ----------------
__global__ __launch_bounds__(256) void k_proj(
    const float* __restrict__ x,
    const bf16* __restrict__ wqp, const bf16* __restrict__ wkp,
    const bf16* __restrict__ wvp, const bf16* __restrict__ wskp,
    const float* __restrict__ bq, const float* __restrict__ bk,
    const float* __restrict__ bv, const float* __restrict__ bsk,
    bf16* __restrict__ qb, bf16* __restrict__ kb, bf16* __restrict__ vb,
    bf16* __restrict__ skipb)
{
    __shared__ __align__(16) short xs[32][136];
    __shared__ __align__(16) short os[32][520];
    const int t = threadIdx.x;
    const int wave = t >> 6, lane = t & 63;
    const int quad = lane >> 4, m = lane & 15;
    const int n0 = blockIdx.x * 32;

    for (int idx = t; idx < 32 * 32; idx += 256) {
        int row = idx >> 5, g = idx & 31;
        int node = n0 + row;
        float4 xv = {0.f, 0.f, 0.f, 0.f};
        if (node < NN) xv = *reinterpret_cast<const float4*>(&x[(size_t)node * 128 + g * 4]);
        short4 s4;
        s4.x = f2bs(xv.x); s4.y = f2bs(xv.y); s4.z = f2bs(xv.z); s4.w = f2bs(xv.w);
        *reinterpret_cast<short4*>(&xs[row][g * 4]) = s4;
    }
    __syncthreads();

    const bf16* Wp = (wave == 0) ? wqp : (wave == 1) ? wkp : (wave == 2) ? wvp : wskp;
    const float* bias = (wave == 0) ? bq : (wave == 1) ? bk : (wave == 2) ? bv : bsk;

    floatx4 acc[2][8];
#pragma unroll
    for (int mt = 0; mt < 2; ++mt)
#pragma unroll
        for (int nt = 0; nt < 8; ++nt) acc[mt][nt] = (floatx4){0.f, 0.f, 0.f, 0.f};

#pragma unroll
    for (int kstep = 0; kstep < 4; ++kstep) {
        short8 af0 = *reinterpret_cast<const short8*>(&xs[m][kstep * 32 + quad * 8]);
        short8 af1 = *reinterpret_cast<const short8*>(&xs[16 + m][kstep * 32 + quad * 8]);
#pragma unroll
        for (int nt = 0; nt < 8; ++nt) {
            short8 bf = *reinterpret_cast<const short8*>(
                reinterpret_cast<const short*>(Wp) + ((nt * 4 + kstep) * 64 + lane) * 8);
            acc[0][nt] = __builtin_amdgcn_mfma_f32_16x16x32_bf16(af0, bf, acc[0][nt], 0, 0, 0);
            acc[1][nt] = __builtin_amdgcn_mfma_f32_16x16x32_bf16(af1, bf, acc[1][nt], 0, 0, 0);
        }
    }
#pragma unroll
    for (int nt = 0; nt < 8; ++nt) {
        float bs = bias[nt * 16 + m];
#pragma unroll
        for (int mt = 0; mt < 2; ++mt)
#pragma unroll
            for (int r = 0; r < 4; ++r)
                os[mt * 16 + quad * 4 + r][wave * 128 + nt * 16 + m] = f2bs(acc[mt][nt][r] + bs);
    }
    __syncthreads();
    for (int idx = t; idx < 32 * 64; idx += 256) {
        int row = idx >> 6, g = idx & 63;
        int node = n0 + row;
        if (node >= NN) continue;
        int col0 = g * 8;
        bf16* dst = (col0 < 128) ? qb : (col0 < 256) ? kb : (col0 < 384) ? vb : skipb;
        *reinterpret_cast<float4*>(&dst[(size_t)node * 128 + (col0 & 127)]) =
            *reinterpret_cast<const float4*>(&os[row][col0]);
    }
}

// ---------------- CSR build ----------------
__global__ void k_hist(const int* __restrict__ ei, const int* __restrict__ flag,
                       int* __restrict__ deg)
{
    int i = blockIdx.x * 256 + threadIdx.x;
    if (i >= EE) return;
    atomicAdd(&deg[load_dst(ei, flag[0], i)], 1);
}

__global__ __launch_bounds__(1024) void k_scan(const int* __restrict__ deg,
                                               int* __restrict__ rowstart)
{
    __shared__ int s[1024];
    const int t = threadIdx.x;
    const int CH = 49;
    int base = t * CH;
    int sum = 0;
    for (int i = 0; i < CH; i++) {
        int idx = base + i;
        if (idx < NN) sum += deg[idx];
    }
    s[t] = sum;
    __syncthreads();
    int own = sum;
    for (int off = 1; off < 1024; off <<= 1) {
        int v = (t >= off) ? s[t - off] : 0;
        __syncthreads();
        s[t] += v;
        __syncthreads();
    }
    int run = s[t] - own;
    for (int i = 0; i < CH; i++) {
        int idx = base + i;
        if (idx < NN) {
            rowstart[idx] = run;
            run += deg[idx];
        }
    }
    if (t == 0) rowstart[NN] = EE;
}

__global__ void k_scatter(const int* __restrict__ ei, const int* __restrict__ flag,
                          const int* __restrict__ rowstart,
                          int* __restrict__ cursor, int* __restrict__ srcs,
                          int* __restrict__ eids)
{
    int i = blockIdx.x * 256 + threadIdx.x;
    if (i >= EE) return;
    int is64 = flag[0];
    int d = load_dst(ei, is64, i);
    int pos = rowstart[d] + atomicAdd(&cursor[d], 1);
    srcs[pos] = load_src(ei, is64, i);
    eids[pos] = i;
}

// ---------------- e = edge_attr @ We, CSR-ordered output (MFMA) ----------------
__global__ __launch_bounds__(256) void k_egemm(
    const float* __restrict__ edge_attr, const float* __restrict__ We,
    const int* __restrict__ eids, bf16* __restrict__ eb)
{
    __shared__ __align__(16) short lds[4][16][136];
    const int t = threadIdx.x;
    const int wave = t >> 6, lane = t & 63;
    const int quad = lane >> 4, m = lane & 15;
    const int p0 = blockIdx.x * 64 + wave * 16;

    short8 Bf[8];
#pragma unroll
    for (int tile = 0; tile < 8; ++tile) {
#pragma unroll
        for (int j = 0; j < 8; ++j)
            Bf[tile][j] = f2bs(We[(quad * 8 + j) * 128 + tile * 16 + m]);
    }
    int eid = eids[p0 + m];
    const float* arow = edge_attr + (size_t)eid * 32 + quad * 8;
    float4 a0 = *reinterpret_cast<const float4*>(arow);
    float4 a1 = *reinterpret_cast<const float4*>(arow + 4);
    short8 Af;
    Af[0] = f2bs(a0.x); Af[1] = f2bs(a0.y); Af[2] = f2bs(a0.z); Af[3] = f2bs(a0.w);
    Af[4] = f2bs(a1.x); Af[5] = f2bs(a1.y); Af[6] = f2bs(a1.z); Af[7] = f2bs(a1.w);

#pragma unroll
    for (int tile = 0; tile < 8; ++tile) {
        floatx4 C = {0.f, 0.f, 0.f, 0.f};
        C = __builtin_amdgcn_mfma_f32_16x16x32_bf16(Af, Bf[tile], C, 0, 0, 0);
#pragma unroll
        for (int r = 0; r < 4; ++r)
            lds[wave][quad * 4 + r][tile * 16 + m] = f2bs(C[r]);
    }
    __syncthreads();
#pragma unroll
    for (int pass = 0; pass < 4; ++pass) {
        int row = pass * 4 + quad;
        float4 vdat = *reinterpret_cast<const float4*>(&lds[wave][row][m * 8]);
        *reinterpret_cast<float4*>(&eb[(size_t)(p0 + row) * 128 + m * 8]) = vdat;
    }
}

// -------- attention (streaming e, online softmax, 2-wide pipeline) + LN1 --------
__global__ __launch_bounds__(128) void k_attn(
    const float* __restrict__ x,
    const bf16* __restrict__ qb, const bf16* __restrict__ kb,
    const bf16* __restrict__ vb, const bf16* __restrict__ skipb,
    const bf16* __restrict__ eb,
    const int* __restrict__ rowstart, const int* __restrict__ srcs,
    const float* __restrict__ ln1g, const float* __restrict__ ln1b,
    bf16* __restrict__ hb)
{
    const int n = blockIdx.x;
    const int t = threadIdx.x;
    const int lane = t & 63;
    float q_t = b2f(qb[n * 128 + t]);
    const int eoff = rowstart[n], eend = rowstart[n + 1];
    float m = -1e30f, l = 0.f, acc = 0.f;
    for (int p = eoff; p < eend; p += 2) {
        const bool has1 = (p + 1 < eend);
        int s0 = srcs[p];
        int s1 = has1 ? srcs[p + 1] : s0;
        int p1i = has1 ? p + 1 : p;
        float e0 = b2f(eb[(size_t)p * 128 + t]);
        float e1 = b2f(eb[(size_t)p1i * 128 + t]);
        float k0 = b2f(kb[s0 * 128 + t]);
        float k1 = b2f(kb[s1 * 128 + t]);
        float v0 = b2f(vb[s0 * 128 + t]);
        float v1 = b2f(vb[s1 * 128 + t]);
        float pr0 = q_t * (k0 + e0);
        float pr1 = q_t * (k1 + e1);
        pr0 += __shfl_xor(pr0, 1); pr1 += __shfl_xor(pr1, 1);
        pr0 += __shfl_xor(pr0, 2); pr1 += __shfl_xor(pr1, 2);
        pr0 += __shfl_xor(pr0, 4); pr1 += __shfl_xor(pr1, 4);
        pr0 += __shfl_xor(pr0, 8); pr1 += __shfl_xor(pr1, 8);
        float a0 = pr0 * 0.25f;
        float a1 = pr1 * 0.25f;
        float m2, l2, acc2;
        if (has1) {
            m2 = fmaxf(a0, a1);
            float w0 = __expf(a0 - m2), w1 = __expf(a1 - m2);
            l2 = w0 + w1;
            acc2 = (v0 + e0) * w0 + (v1 + e1) * w1;
        } else {
            m2 = a0; l2 = 1.f; acc2 = v0 + e0;
        }
        float mn = fmaxf(m, m2);
        float sA = __expf(m - mn), sB = __expf(m2 - mn);
        l = l * sA + l2 * sB;
        acc = acc * sA + acc2 * sB;
        m = mn;
    }
    float attn = acc / (l + 1e-16f);
    float pre = x[n * 128 + t] + attn + b2f(skipb[n * 128 + t]);
    float s1 = pre, s2 = pre * pre;
#pragma unroll
    for (int off = 1; off < 64; off <<= 1) {
        s1 += __shfl_xor(s1, off);
        s2 += __shfl_xor(s2, off);
    }
    __shared__ float r1[2], r2[2];
    const int wid = t >> 6;
    if (lane == 0) { r1[wid] = s1; r2[wid] = s2; }
    __syncthreads();
    float mu = (r1[0] + r1[1]) * (1.f / 128.f);
    float ms = (r2[0] + r2[1]) * (1.f / 128.f);
    float var = ms - mu * mu;
    float inv = rsqrtf(var + 1e-5f);
    float h = (pre - mu) * inv * ln1g[t] + ln1b[t];
    hb[n * 128 + t] = __float2bfloat16(h);
}

// -------- fallback attention (recompute e in-loop) for small ws --------
__global__ __launch_bounds__(128) void k_attn_noeb(
    const float* __restrict__ x, const float* __restrict__ edge_attr,
    const float* __restrict__ We,
    const bf16* __restrict__ qb, const bf16* __restrict__ kb,
    const bf16* __restrict__ vb, const bf16* __restrict__ skipb,
    const int* __restrict__ rowstart, const int* __restrict__ srcs,
    const int* __restrict__ eids,
    const float* __restrict__ ln1g, const float* __restrict__ ln1b,
    bf16* __restrict__ hb)
{
    const int n = blockIdx.x;
    const int t = threadIdx.x;
    const int lane = t & 63;
    float we[32];
#pragma unroll
    for (int d = 0; d < 32; ++d) we[d] = We[d * 128 + t];
    float q_t = b2f(qb[n * 128 + t]);
    const int eoff = rowstart[n], eend = rowstart[n + 1];
    float m = -1e30f, l = 0.f, acc = 0.f;
    for (int p = eoff; p < eend; ++p) {
        int src = srcs[p];
        int eid = eids[p];
        float eav = edge_attr[eid * 32 + (lane & 31)];
        float e_t = 0.f;
#pragma unroll
        for (int d = 0; d < 32; ++d) e_t = fmaf(we[d], __shfl(eav, d), e_t);
        float ke = b2f(kb[src * 128 + t]) + e_t;
        float prod = q_t * ke;
        prod += __shfl_xor(prod, 1);
        prod += __shfl_xor(prod, 2);
        prod += __shfl_xor(prod, 4);
        prod += __shfl_xor(prod, 8);
        float alpha = prod * 0.25f;
        float mn = fmaxf(m, alpha);
        float sc = __expf(m - mn);
        float pw = __expf(alpha - mn);
        l = l * sc + pw;
        float ve = b2f(vb[src * 128 + t]) + e_t;
        acc = acc * sc + ve * pw;
        m = mn;
    }
    float attn = acc / (l + 1e-16f);
    float pre = x[n * 128 + t] + attn + b2f(skipb[n * 128 + t]);
    float s1 = pre, s2 = pre * pre;
#pragma unroll
    for (int off = 1; off < 64; off <<= 1) {
        s1 += __shfl_xor(s1, off);
        s2 += __shfl_xor(s2, off);
    }
    __shared__ float r1[2], r2[2];
    const int wid = t >> 6;
    if (lane == 0) { r1[wid] = s1; r2[wid] = s2; }
    __syncthreads();
    float mu = (r1[0] + r1[1]) * (1.f / 128.f);
    float ms = (r2[0] + r2[1]) * (1.f / 128.f);
    float var = ms - mu * mu;
    float inv = rsqrtf(var + 1e-5f);
    float h = (pre - mu) * inv * ln1g[t] + ln1b[t];
    hb[n * 128 + t] = __float2bfloat16(h);
}

// ---------------- FFN via MFMA + LN2 ----------------
__global__ __launch_bounds__(256) void k_ffn(
    const bf16* __restrict__ hb,
    const bf16* __restrict__ w1p, const float* __restrict__ b1,
    const bf16* __restrict__ w2p, const float* __restrict__ b2,
    const float* __restrict__ ln2g, const float* __restrict__ ln2b,
    float* __restrict__ out)
{
    __shared__ __align__(16) short hs[32][136];
    __shared__ __align__(16) short t1s[32][520];
    float* fs = reinterpret_cast<float*>(&t1s[0][0]);  // [32][132] after t1s is dead
    const int t = threadIdx.x;
    const int wave = t >> 6, lane = t & 63;
    const int quad = lane >> 4, m = lane & 15;
    const int n0 = blockIdx.x * 32;

    for (int idx = t; idx < 32 * 16; idx += 256) {
        int row = idx >> 4, g = idx & 15;
        int node = n0 + row;
        if (node < NN) {
            *reinterpret_cast<float4*>(&hs[row][g * 8]) =
                *reinterpret_cast<const float4*>(&hb[(size_t)node * 128 + g * 8]);
        } else {
            float4 z = {0.f, 0.f, 0.f, 0.f};
            *reinterpret_cast<float4*>(&hs[row][g * 8]) = z;
        }
    }
    __syncthreads();

    // GEMM1: [32x128] @ [128x512], wave owns cols wave*128..+127
    floatx4 acc1[2][8];
#pragma unroll
    for (int mt = 0; mt < 2; ++mt)
#pragma unroll
        for (int nt = 0; nt < 8; ++nt) acc1[mt][nt] = (floatx4){0.f, 0.f, 0.f, 0.f};
#pragma unroll
    for (int kstep = 0; kstep < 4; ++kstep) {
        short8 af0 = *reinterpret_cast<const short8*>(&hs[m][kstep * 32 + quad * 8]);
        short8 af1 = *reinterpret_cast<const short8*>(&hs[16 + m][kstep * 32 + quad * 8]);
#pragma unroll
        for (int nt = 0; nt < 8; ++nt) {
            short8 bf = *reinterpret_cast<const short8*>(
                reinterpret_cast<const short*>(w1p) + (((wave * 8 + nt) * 4 + kstep) * 64 + lane) * 8);
            acc1[0][nt] = __builtin_amdgcn_mfma_f32_16x16x32_bf16(af0, bf, acc1[0][nt], 0, 0, 0);
            acc1[1][nt] = __builtin_amdgcn_mfma_f32_16x16x32_bf16(af1, bf, acc1[1][nt], 0, 0, 0);
        }
    }
#pragma unroll
    for (int nt = 0; nt < 8; ++nt) {
        float bs = b1[wave * 128 + nt * 16 + m];
#pragma unroll
        for (int mt = 0; mt < 2; ++mt)
#pragma unroll
            for (int r = 0; r < 4; ++r)
                t1s[mt * 16 + quad * 4 + r][wave * 128 + nt * 16 + m] =
                    f2bs(fmaxf(acc1[mt][nt][r] + bs, 0.f));
    }
    __syncthreads();

    // GEMM2: [32x512] @ [512x128], wave owns cols wave*32..+31
    floatx4 acc2[2][2];
#pragma unroll
    for (int mt = 0; mt < 2; ++mt)
#pragma unroll
        for (int nt = 0; nt < 2; ++nt) acc2[mt][nt] = (floatx4){0.f, 0.f, 0.f, 0.f};
#pragma unroll
    for (int kstep = 0; kstep < 16; ++kstep) {
        short8 af0 = *reinterpret_cast<const short8*>(&t1s[m][kstep * 32 + quad * 8]);
        short8 af1 = *reinterpret_cast<const short8*>(&t1s[16 + m][kstep * 32 + quad * 8]);
#pragma unroll
        for (int nt = 0; nt < 2; ++nt) {
            short8 bf = *reinterpret_cast<const short8*>(
                reinterpret_cast<const short*>(w2p) + (((wave * 2 + nt) * 16 + kstep) * 64 + lane) * 8);
            acc2[0][nt] = __builtin_amdgcn_mfma_f32_16x16x32_bf16(af0, bf, acc2[0][nt], 0, 0, 0);
            acc2[1][nt] = __builtin_amdgcn_mfma_f32_16x16x32_bf16(af1, bf, acc2[1][nt], 0, 0, 0);
        }
    }
    __syncthreads();  // all waves done reading t1s; fs aliases it
#pragma unroll
    for (int nt = 0; nt < 2; ++nt) {
        int col = (wave * 2 + nt) * 16 + m;
        float bs = b2[col];
#pragma unroll
        for (int mt = 0; mt < 2; ++mt)
#pragma unroll
            for (int r = 0; r < 4; ++r)
                fs[(mt * 16 + quad * 4 + r) * 132 + col] = acc2[mt][nt][r] + bs;
    }
    __syncthreads();

    // LN2: wave handles 8 rows
    for (int rr = 0; rr < 8; ++rr) {
        int row = wave * 8 + rr;
        int node = n0 + row;
        float p0 = bs2f(hs[row][lane]) + fs[row * 132 + lane];
        float p1 = bs2f(hs[row][lane + 64]) + fs[row * 132 + lane + 64];
        float s1 = p0 + p1, s2 = p0 * p0 + p1 * p1;
#pragma unroll
        for (int off = 1; off < 64; off <<= 1) {
            s1 += __shfl_xor(s1, off);
            s2 += __shfl_xor(s2, off);
        }
        float mu = s1 * (1.f / 128.f);
        float var = s2 * (1.f / 128.f) - mu * mu;
        float inv = rsqrtf(var + 1e-5f);
        if (node < NN) {
            out[(size_t)node * 128 + lane] = (p0 - mu) * inv * ln2g[lane] + ln2b[lane];
            out[(size_t)node * 128 + lane + 64] = (p1 - mu) * inv * ln2g[lane + 64] + ln2b[lane + 64];
        }
    }
}

extern "C" void kernel_launch(void* const* d_in, const int* in_sizes, int n_in,
                              void* d_out, int out_size, void* d_ws, size_t ws_size,
                              hipStream_t stream)
{
    const float* x    = (const float*)d_in[0];
    const int*   ei   = (const int*)d_in[1];
    const float* ea   = (const float*)d_in[2];
    const float* Wq   = (const float*)d_in[3];
    const float* bq   = (const float*)d_in[4];
    const float* Wk   = (const float*)d_in[5];
    const float* bk   = (const float*)d_in[6];
    const float* Wv   = (const float*)d_in[7];
    const float* bv   = (const float*)d_in[8];
    const float* We   = (const float*)d_in[9];
    const float* Wsk  = (const float*)d_in[10];
    const float* bsk  = (const float*)d_in[11];
    const float* ln1g = (const float*)d_in[12];
    const float* ln1b = (const float*)d_in[13];
    const float* W1   = (const float*)d_in[14];
    const float* b1   = (const float*)d_in[15];
    const float* W2   = (const float*)d_in[16];
    const float* b2   = (const float*)d_in[17];
    const float* ln2g = (const float*)d_in[18];
    const float* ln2b = (const float*)d_in[19];

    char* ws = (char*)d_ws;
    size_t off = 0;
    auto alloc = [&](size_t bytes) -> void* {
        void* p = ws + off;
        off += (bytes + 255) & ~(size_t)255;
        return p;
    };
    int*   flag     = (int*)alloc(256);
    int*   deg      = (int*)alloc((size_t)NN * 4);
    int*   cursor   = (int*)alloc((size_t)NN * 4);
    int*   rowstart = (int*)alloc((size_t)(NN + 1) * 4);
    int*   srcs     = (int*)alloc((size_t)EE * 4);
    int*   eids     = (int*)alloc((size_t)EE * 4);
    bf16*  qb       = (bf16*)alloc((size_t)NN * 128 * 2);
    bf16*  kb       = (bf16*)alloc((size_t)NN * 128 * 2);
    bf16*  vb       = (bf16*)alloc((size_t)NN * 128 * 2);
    bf16*  skipb    = (bf16*)alloc((size_t)NN * 128 * 2);
    bf16*  hb       = (bf16*)alloc((size_t)NN * 128 * 2);
    bf16*  wqp      = (bf16*)alloc((size_t)16384 * 2);
    bf16*  wkp      = (bf16*)alloc((size_t)16384 * 2);
    bf16*  wvp      = (bf16*)alloc((size_t)16384 * 2);
    bf16*  wskp     = (bf16*)alloc((size_t)16384 * 2);
    bf16*  w1p      = (bf16*)alloc((size_t)65536 * 2);
    bf16*  w2p      = (bf16*)alloc((size_t)65536 * 2);
    bf16*  eb       = (bf16*)alloc((size_t)EE * 128 * 2);
    const bool use_eb = (off <= ws_size);

    hipMemsetAsync(deg, 0, (size_t)NN * 4, stream);
    hipMemsetAsync(cursor, 0, (size_t)NN * 4, stream);

    k_detect<<<1, 64, 0, stream>>>(ei, flag);
    k_hist<<<(EE + 255) / 256, 256, 0, stream>>>(ei, flag, deg);

    k_pack<<<(16384 + 255) / 256, 256, 0, stream>>>(Wq, wqp, 4, 128, 16384);
    k_pack<<<(16384 + 255) / 256, 256, 0, stream>>>(Wk, wkp, 4, 128, 16384);
    k_pack<<<(16384 + 255) / 256, 256, 0, stream>>>(Wv, wvp, 4, 128, 16384);
    k_pack<<<(16384 + 255) / 256, 256, 0, stream>>>(Wsk, wskp, 4, 128, 16384);
    k_pack<<<(65536 + 255) / 256, 256, 0, stream>>>(W1, w1p, 4, 512, 65536);
    k_pack<<<(65536 + 255) / 256, 256, 0, stream>>>(W2, w2p, 16, 128, 65536);

    k_proj<<<(NN + 31) / 32, 256, 0, stream>>>(x, wqp, wkp, wvp, wskp,
                                               bq, bk, bv, bsk, qb, kb, vb, skipb);
    k_scan<<<1, 1024, 0, stream>>>(deg, rowstart);
    k_scatter<<<(EE + 255) / 256, 256, 0, stream>>>(ei, flag, rowstart, cursor, srcs, eids);
    if (use_eb) {
        k_egemm<<<EE / 64, 256, 0, stream>>>(ea, We, eids, eb);
        k_attn<<<NN, 128, 0, stream>>>(x, qb, kb, vb, skipb, eb,
                                       rowstart, srcs, ln1g, ln1b, hb);
    } else {
        k_attn_noeb<<<NN, 128, 0, stream>>>(x, ea, We, qb, kb, vb, skipb,
                                            rowstart, srcs, eids, ln1g, ln1b, hb);
    }
    k_ffn<<<(NN + 31) / 32, 256, 0, stream>>>(hb, w1p, b1, w2p, b2, ln2g, ln2b, (float*)d_out);
}

// Round 5
// 624.197 us; speedup vs baseline: 2.2082x; 1.1838x over previous
//
#include <hip/hip_runtime.h>
#include <hip/hip_bf16.h>

using bf16 = __hip_bfloat16;
typedef __attribute__((ext_vector_type(8))) short short8;
typedef __attribute__((ext_vector_type(4))) float floatx4;

#define NN 50000
#define EE 800000
#define DD 128
#define HH 8
#define CC 16
#define EDD 32
#define DF 512

__device__ __forceinline__ float b2f(bf16 v) { return __bfloat162float(v); }
__device__ __forceinline__ float bs2f(short s) {
    bf16 h = *reinterpret_cast<bf16*>(&s);
    return __bfloat162float(h);
}
__device__ __forceinline__ float bu2f(unsigned short s) {
    unsigned int u = ((unsigned int)s) << 16;
    return *reinterpret_cast<float*>(&u);
}
__device__ __forceinline__ short f2bs(float v) {
    bf16 h = __float2bfloat16(v);
    return *reinterpret_cast<short*>(&h);
}

// ---- edge_index width detection: int64 has zero high-words (values < 50000)
__global__ void k_detect(const int* __restrict__ ei, int* __restrict__ flag)
{
    if (threadIdx.x == 0 && blockIdx.x == 0) {
        int all0 = 1;
        for (int i = 0; i < 16; ++i) all0 &= (ei[2 * i + 1] == 0);
        flag[0] = all0;  // 1 => int64 layout, 0 => int32
    }
}

__device__ __forceinline__ int load_src(const int* ei, int is64, int i)
{
    int s = is64 ? ei[2 * i] : ei[i];
    return (s < 0) ? 0 : (s >= NN ? NN - 1 : s);
}
__device__ __forceinline__ int load_dst(const int* ei, int is64, int i)
{
    int d = is64 ? ei[2 * EE + 2 * i] : ei[EE + i];
    return (d < 0) ? 0 : (d >= NN ? NN - 1 : d);
}

// ---- pack ALL fp32 weights [K][N] into per-lane MFMA B-frag layout (bf16) ----
// frag (ntile,kstep): 64 lanes x 8 bf16, lane=(quad,m): B[k=kstep*32+quad*8+j][n=ntile*16+m]
__global__ void k_packall(const float* __restrict__ Wq, const float* __restrict__ Wk,
                          const float* __restrict__ Wv, const float* __restrict__ Wsk,
                          const float* __restrict__ W1, const float* __restrict__ W2,
                          const float* __restrict__ We,
                          bf16* __restrict__ wqp, bf16* __restrict__ wkp,
                          bf16* __restrict__ wvp, bf16* __restrict__ wskp,
                          bf16* __restrict__ w1p, bf16* __restrict__ w2p,
                          bf16* __restrict__ wep)
{
    int idx = blockIdx.x * 256 + threadIdx.x;
    const float* W; bf16* out; int ksteps, N, local;
    if (idx < 65536) {
        int wsel = idx >> 14; local = idx & 16383;
        W   = (wsel == 0) ? Wq  : (wsel == 1) ? Wk  : (wsel == 2) ? Wv  : Wsk;
        out = (wsel == 0) ? wqp : (wsel == 1) ? wkp : (wsel == 2) ? wvp : wskp;
        ksteps = 4; N = 128;
    } else if (idx < 131072) { local = idx - 65536;  W = W1; out = w1p; ksteps = 4;  N = 512; }
    else if (idx < 196608)   { local = idx - 131072; W = W2; out = w2p; ksteps = 16; N = 128; }
    else if (idx < 200704)   { local = idx - 196608; W = We; out = wep; ksteps = 1;  N = 128; }
    else return;
    int j = local & 7, lane = (local >> 3) & 63, rest = local >> 9;
    int kstep = rest % ksteps, ntile = rest / ksteps;
    int quad = lane >> 4, m = lane & 15;
    int k = kstep * 32 + quad * 8 + j;
    int n = ntile * 16 + m;
    out[local] = __float2bfloat16(W[(size_t)k * N + n]);
}

// ---------------- projections via MFMA: q,k,v,skip (all bf16) ----------------
__global__ __launch_bounds__(256) void k_proj(
    const float* __restrict__ x,
    const bf16* __restrict__ wqp, const bf16* __restrict__ wkp,
    const bf16* __restrict__ wvp, const bf16* __restrict__ wskp,
    const float* __restrict__ bq, const float* __restrict__ bk,
    const float* __restrict__ bv, const float* __restrict__ bsk,
    bf16* __restrict__ qb, bf16* __restrict__ kb, bf16* __restrict__ vb,
    bf16* __restrict__ skipb)
{
    __shared__ __align__(16) short xs[32][136];
    __shared__ __align__(16) short os[32][520];
    const int t = threadIdx.x;
    const int wave = t >> 6, lane = t & 63;
    const int quad = lane >> 4, m = lane & 15;
    const int n0 = blockIdx.x * 32;

    for (int idx = t; idx < 32 * 32; idx += 256) {
        int row = idx >> 5, g = idx & 31;
        int node = n0 + row;
        float4 xv = {0.f, 0.f, 0.f, 0.f};
        if (node < NN) xv = *reinterpret_cast<const float4*>(&x[(size_t)node * 128 + g * 4]);
        short4 s4;
        s4.x = f2bs(xv.x); s4.y = f2bs(xv.y); s4.z = f2bs(xv.z); s4.w = f2bs(xv.w);
        *reinterpret_cast<short4*>(&xs[row][g * 4]) = s4;
    }
    __syncthreads();

    const bf16* Wp = (wave == 0) ? wqp : (wave == 1) ? wkp : (wave == 2) ? wvp : wskp;
    const float* bias = (wave == 0) ? bq : (wave == 1) ? bk : (wave == 2) ? bv : bsk;

    floatx4 acc[2][8];
#pragma unroll
    for (int mt = 0; mt < 2; ++mt)
#pragma unroll
        for (int nt = 0; nt < 8; ++nt) acc[mt][nt] = (floatx4){0.f, 0.f, 0.f, 0.f};

#pragma unroll
    for (int kstep = 0; kstep < 4; ++kstep) {
        short8 af0 = *reinterpret_cast<const short8*>(&xs[m][kstep * 32 + quad * 8]);
        short8 af1 = *reinterpret_cast<const short8*>(&xs[16 + m][kstep * 32 + quad * 8]);
#pragma unroll
        for (int nt = 0; nt < 8; ++nt) {
            short8 bf = *reinterpret_cast<const short8*>(
                reinterpret_cast<const short*>(Wp) + ((nt * 4 + kstep) * 64 + lane) * 8);
            acc[0][nt] = __builtin_amdgcn_mfma_f32_16x16x32_bf16(af0, bf, acc[0][nt], 0, 0, 0);
            acc[1][nt] = __builtin_amdgcn_mfma_f32_16x16x32_bf16(af1, bf, acc[1][nt], 0, 0, 0);
        }
    }
#pragma unroll
    for (int nt = 0; nt < 8; ++nt) {
        float bs = bias[nt * 16 + m];
#pragma unroll
        for (int mt = 0; mt < 2; ++mt)
#pragma unroll
            for (int r = 0; r < 4; ++r)
                os[mt * 16 + quad * 4 + r][wave * 128 + nt * 16 + m] = f2bs(acc[mt][nt][r] + bs);
    }
    __syncthreads();
    for (int idx = t; idx < 32 * 64; idx += 256) {
        int row = idx >> 6, g = idx & 63;
        int node = n0 + row;
        if (node >= NN) continue;
        int col0 = g * 8;
        bf16* dst = (col0 < 128) ? qb : (col0 < 256) ? kb : (col0 < 384) ? vb : skipb;
        *reinterpret_cast<float4*>(&dst[(size_t)node * 128 + (col0 & 127)]) =
            *reinterpret_cast<const float4*>(&os[row][col0]);
    }
}

// ---------------- CSR build ----------------
__global__ void k_hist(const int* __restrict__ ei, const int* __restrict__ flag,
                       int* __restrict__ deg)
{
    int i = blockIdx.x * 256 + threadIdx.x;
    if (i >= EE) return;
    atomicAdd(&deg[load_dst(ei, flag[0], i)], 1);
}

__global__ __launch_bounds__(1024) void k_scan(const int* __restrict__ deg,
                                               int* __restrict__ rowstart)
{
    __shared__ int s[1024];
    const int t = threadIdx.x;
    const int CH = 49;
    int base = t * CH;
    int sum = 0;
    for (int i = 0; i < CH; i++) {
        int idx = base + i;
        if (idx < NN) sum += deg[idx];
    }
    s[t] = sum;
    __syncthreads();
    int own = sum;
    for (int off = 1; off < 1024; off <<= 1) {
        int v = (t >= off) ? s[t - off] : 0;
        __syncthreads();
        s[t] += v;
        __syncthreads();
    }
    int run = s[t] - own;
    for (int i = 0; i < CH; i++) {
        int idx = base + i;
        if (idx < NN) {
            rowstart[idx] = run;
            run += deg[idx];
        }
    }
    if (t == 0) rowstart[NN] = EE;
}

__global__ void k_scatter(const int* __restrict__ ei, const int* __restrict__ flag,
                          const int* __restrict__ rowstart,
                          int* __restrict__ cursor, int* __restrict__ srcs,
                          int* __restrict__ eids)
{
    int i = blockIdx.x * 256 + threadIdx.x;
    if (i >= EE) return;
    int is64 = flag[0];
    int d = load_dst(ei, is64, i);
    int pos = rowstart[d] + atomicAdd(&cursor[d], 1);
    srcs[pos] = load_src(ei, is64, i);
    eids[pos] = i;
}

// -------- fused attention: in-tile MFMA e-GEMM + direct-exp softmax + LN1 --------
// block = 128 threads = 2 waves; one dst node per block; edges in tiles of 16.
__global__ __launch_bounds__(128) void k_attn(
    const float* __restrict__ x, const float* __restrict__ edge_attr,
    const bf16* __restrict__ wep,
    const bf16* __restrict__ qb, const bf16* __restrict__ kb,
    const bf16* __restrict__ vb, const bf16* __restrict__ skipb,
    const int* __restrict__ rowstart, const int* __restrict__ srcs,
    const int* __restrict__ eids,
    const float* __restrict__ ln1g, const float* __restrict__ ln1b,
    bf16* __restrict__ hb)
{
    __shared__ __align__(16) short es[16][136];
    __shared__ int ss[16];
    __shared__ float r1[2], r2[2];
    const int n = blockIdx.x;
    const int t = threadIdx.x;     // channel 0..127; head = t>>4
    const int wave = t >> 6, lane = t & 63;
    const int quad = lane >> 4, m = lane & 15;

    // We B-frags for this wave's 4 ntiles (channels wave*64 .. wave*64+63)
    short8 Bf[4];
#pragma unroll
    for (int ntl = 0; ntl < 4; ++ntl) {
        int nt = wave * 4 + ntl;
        Bf[ntl] = *reinterpret_cast<const short8*>(
            reinterpret_cast<const short*>(wep) + (nt * 64 + lane) * 8);
    }
    float q_t = b2f(qb[n * 128 + t]);
    const int eoff = rowstart[n], eend = rowstart[n + 1];
    const unsigned short* kbu = reinterpret_cast<const unsigned short*>(kb);
    const unsigned short* vbu = reinterpret_cast<const unsigned short*>(vb);
    float l = 0.f, acc = 0.f;

    for (int p0 = eoff; p0 < eend; p0 += 16) {
        // A-frag: row m = CSR position p0+m, k = quad*8+j (clamped when past end)
        int pos = p0 + m;
        int pc = (pos < eend) ? pos : eoff;
        int eid = eids[pc];
        const float* arow = edge_attr + (size_t)eid * 32 + quad * 8;
        float4 a0 = *reinterpret_cast<const float4*>(arow);
        float4 a1 = *reinterpret_cast<const float4*>(arow + 4);
        short8 Af;
        Af[0] = f2bs(a0.x); Af[1] = f2bs(a0.y); Af[2] = f2bs(a0.z); Af[3] = f2bs(a0.w);
        Af[4] = f2bs(a1.x); Af[5] = f2bs(a1.y); Af[6] = f2bs(a1.z); Af[7] = f2bs(a1.w);
        if (t < 16) ss[t] = srcs[(p0 + t < eend) ? p0 + t : eoff];
#pragma unroll
        for (int ntl = 0; ntl < 4; ++ntl) {
            floatx4 C = {0.f, 0.f, 0.f, 0.f};
            C = __builtin_amdgcn_mfma_f32_16x16x32_bf16(Af, Bf[ntl], C, 0, 0, 0);
            int col = (wave * 4 + ntl) * 16 + m;
#pragma unroll
            for (int r = 0; r < 4; ++r)
                es[quad * 4 + r][col] = f2bs(C[r]);   // row = edge-in-tile, col = channel
        }
        __syncthreads();
        int cnt = eend - p0; if (cnt > 16) cnt = 16;
        // prefetch all k/v for the tile (32 outstanding loads per thread)
        unsigned short kr[16], vr[16];
#pragma unroll
        for (int j = 0; j < 16; ++j) {
            size_t o = (size_t)ss[j] * 128 + t;
            kr[j] = kbu[o];
            vr[j] = vbu[o];
        }
#pragma unroll
        for (int j = 0; j < 16; ++j) {
            float e = bs2f(es[j][t]);
            float pr = q_t * (bu2f(kr[j]) + e);
            pr += __shfl_xor(pr, 1);
            pr += __shfl_xor(pr, 2);
            pr += __shfl_xor(pr, 4);
            pr += __shfl_xor(pr, 8);
            float w = (j < cnt) ? __expf(pr * 0.25f) : 0.f;  // 1/sqrt(16); alpha bounded, no max needed
            l += w;
            acc = fmaf(bu2f(vr[j]) + e, w, acc);
        }
        __syncthreads();
    }
    float attn = acc / (l + 1e-16f);
    float pre = x[n * 128 + t] + attn + b2f(skipb[n * 128 + t]);
    float s1 = pre, s2 = pre * pre;
#pragma unroll
    for (int off = 1; off < 64; off <<= 1) {
        s1 += __shfl_xor(s1, off);
        s2 += __shfl_xor(s2, off);
    }
    const int wid = t >> 6;
    if (lane == 0) { r1[wid] = s1; r2[wid] = s2; }
    __syncthreads();
    float mu = (r1[0] + r1[1]) * (1.f / 128.f);
    float ms = (r2[0] + r2[1]) * (1.f / 128.f);
    float var = ms - mu * mu;
    float inv = rsqrtf(var + 1e-5f);
    float h = (pre - mu) * inv * ln1g[t] + ln1b[t];
    hb[n * 128 + t] = __float2bfloat16(h);
}

// ---------------- FFN via MFMA + LN2 ----------------
__global__ __launch_bounds__(256) void k_ffn(
    const bf16* __restrict__ hb,
    const bf16* __restrict__ w1p, const float* __restrict__ b1,
    const bf16* __restrict__ w2p, const float* __restrict__ b2,
    const float* __restrict__ ln2g, const float* __restrict__ ln2b,
    float* __restrict__ out)
{
    __shared__ __align__(16) short hs[32][136];
    __shared__ __align__(16) short t1s[32][520];
    float* fs = reinterpret_cast<float*>(&t1s[0][0]);  // [32][132] after t1s is dead
    const int t = threadIdx.x;
    const int wave = t >> 6, lane = t & 63;
    const int quad = lane >> 4, m = lane & 15;
    const int n0 = blockIdx.x * 32;

    for (int idx = t; idx < 32 * 16; idx += 256) {
        int row = idx >> 4, g = idx & 15;
        int node = n0 + row;
        if (node < NN) {
            *reinterpret_cast<float4*>(&hs[row][g * 8]) =
                *reinterpret_cast<const float4*>(&hb[(size_t)node * 128 + g * 8]);
        } else {
            float4 z = {0.f, 0.f, 0.f, 0.f};
            *reinterpret_cast<float4*>(&hs[row][g * 8]) = z;
        }
    }
    __syncthreads();

    floatx4 acc1[2][8];
#pragma unroll
    for (int mt = 0; mt < 2; ++mt)
#pragma unroll
        for (int nt = 0; nt < 8; ++nt) acc1[mt][nt] = (floatx4){0.f, 0.f, 0.f, 0.f};
#pragma unroll
    for (int kstep = 0; kstep < 4; ++kstep) {
        short8 af0 = *reinterpret_cast<const short8*>(&hs[m][kstep * 32 + quad * 8]);
        short8 af1 = *reinterpret_cast<const short8*>(&hs[16 + m][kstep * 32 + quad * 8]);
#pragma unroll
        for (int nt = 0; nt < 8; ++nt) {
            short8 bf = *reinterpret_cast<const short8*>(
                reinterpret_cast<const short*>(w1p) + (((wave * 8 + nt) * 4 + kstep) * 64 + lane) * 8);
            acc1[0][nt] = __builtin_amdgcn_mfma_f32_16x16x32_bf16(af0, bf, acc1[0][nt], 0, 0, 0);
            acc1[1][nt] = __builtin_amdgcn_mfma_f32_16x16x32_bf16(af1, bf, acc1[1][nt], 0, 0, 0);
        }
    }
#pragma unroll
    for (int nt = 0; nt < 8; ++nt) {
        float bs = b1[wave * 128 + nt * 16 + m];
#pragma unroll
        for (int mt = 0; mt < 2; ++mt)
#pragma unroll
            for (int r = 0; r < 4; ++r)
                t1s[mt * 16 + quad * 4 + r][wave * 128 + nt * 16 + m] =
                    f2bs(fmaxf(acc1[mt][nt][r] + bs, 0.f));
    }
    __syncthreads();

    floatx4 acc2[2][2];
#pragma unroll
    for (int mt = 0; mt < 2; ++mt)
#pragma unroll
        for (int nt = 0; nt < 2; ++nt) acc2[mt][nt] = (floatx4){0.f, 0.f, 0.f, 0.f};
#pragma unroll
    for (int kstep = 0; kstep < 16; ++kstep) {
        short8 af0 = *reinterpret_cast<const short8*>(&t1s[m][kstep * 32 + quad * 8]);
        short8 af1 = *reinterpret_cast<const short8*>(&t1s[16 + m][kstep * 32 + quad * 8]);
#pragma unroll
        for (int nt = 0; nt < 2; ++nt) {
            short8 bf = *reinterpret_cast<const short8*>(
                reinterpret_cast<const short*>(w2p) + (((wave * 2 + nt) * 16 + kstep) * 64 + lane) * 8);
            acc2[0][nt] = __builtin_amdgcn_mfma_f32_16x16x32_bf16(af0, bf, acc2[0][nt], 0, 0, 0);
            acc2[1][nt] = __builtin_amdgcn_mfma_f32_16x16x32_bf16(af1, bf, acc2[1][nt], 0, 0, 0);
        }
    }
    __syncthreads();
#pragma unroll
    for (int nt = 0; nt < 2; ++nt) {
        int col = (wave * 2 + nt) * 16 + m;
        float bs = b2[col];
#pragma unroll
        for (int mt = 0; mt < 2; ++mt)
#pragma unroll
            for (int r = 0; r < 4; ++r)
                fs[(mt * 16 + quad * 4 + r) * 132 + col] = acc2[mt][nt][r] + bs;
    }
    __syncthreads();

    for (int rr = 0; rr < 8; ++rr) {
        int row = wave * 8 + rr;
        int node = n0 + row;
        float p0 = bs2f(hs[row][lane]) + fs[row * 132 + lane];
        float p1 = bs2f(hs[row][lane + 64]) + fs[row * 132 + lane + 64];
        float s1 = p0 + p1, s2 = p0 * p0 + p1 * p1;
#pragma unroll
        for (int off = 1; off < 64; off <<= 1) {
            s1 += __shfl_xor(s1, off);
            s2 += __shfl_xor(s2, off);
        }
        float mu = s1 * (1.f / 128.f);
        float var = s2 * (1.f / 128.f) - mu * mu;
        float inv = rsqrtf(var + 1e-5f);
        if (node < NN) {
            out[(size_t)node * 128 + lane] = (p0 - mu) * inv * ln2g[lane] + ln2b[lane];
            out[(size_t)node * 128 + lane + 64] = (p1 - mu) * inv * ln2g[lane + 64] + ln2b[lane + 64];
        }
    }
}

extern "C" void kernel_launch(void* const* d_in, const int* in_sizes, int n_in,
                              void* d_out, int out_size, void* d_ws, size_t ws_size,
                              hipStream_t stream)
{
    const float* x    = (const float*)d_in[0];
    const int*   ei   = (const int*)d_in[1];
    const float* ea   = (const float*)d_in[2];
    const float* Wq   = (const float*)d_in[3];
    const float* bq   = (const float*)d_in[4];
    const float* Wk   = (const float*)d_in[5];
    const float* bk   = (const float*)d_in[6];
    const float* Wv   = (const float*)d_in[7];
    const float* bv   = (const float*)d_in[8];
    const float* We   = (const float*)d_in[9];
    const float* Wsk  = (const float*)d_in[10];
    const float* bsk  = (const float*)d_in[11];
    const float* ln1g = (const float*)d_in[12];
    const float* ln1b = (const float*)d_in[13];
    const float* W1   = (const float*)d_in[14];
    const float* b1   = (const float*)d_in[15];
    const float* W2   = (const float*)d_in[16];
    const float* b2   = (const float*)d_in[17];
    const float* ln2g = (const float*)d_in[18];
    const float* ln2b = (const float*)d_in[19];

    char* ws = (char*)d_ws;
    size_t off = 0;
    auto alloc = [&](size_t bytes) -> void* {
        void* p = ws + off;
        off += (bytes + 255) & ~(size_t)255;
        return p;
    };
    int*   flag     = (int*)alloc(256);
    int*   deg      = (int*)alloc((size_t)NN * 4);
    int*   cursor   = (int*)alloc((size_t)NN * 4);
    int*   rowstart = (int*)alloc((size_t)(NN + 1) * 4);
    int*   srcs     = (int*)alloc((size_t)EE * 4);
    int*   eids     = (int*)alloc((size_t)EE * 4);
    bf16*  qb       = (bf16*)alloc((size_t)NN * 128 * 2);
    bf16*  kb       = (bf16*)alloc((size_t)NN * 128 * 2);
    bf16*  vb       = (bf16*)alloc((size_t)NN * 128 * 2);
    bf16*  skipb    = (bf16*)alloc((size_t)NN * 128 * 2);
    bf16*  hb       = (bf16*)alloc((size_t)NN * 128 * 2);
    bf16*  wqp      = (bf16*)alloc((size_t)16384 * 2);
    bf16*  wkp      = (bf16*)alloc((size_t)16384 * 2);
    bf16*  wvp      = (bf16*)alloc((size_t)16384 * 2);
    bf16*  wskp     = (bf16*)alloc((size_t)16384 * 2);
    bf16*  w1p      = (bf16*)alloc((size_t)65536 * 2);
    bf16*  w2p      = (bf16*)alloc((size_t)65536 * 2);
    bf16*  wep      = (bf16*)alloc((size_t)4096 * 2);

    hipMemsetAsync(deg, 0, (size_t)NN * 4, stream);
    hipMemsetAsync(cursor, 0, (size_t)NN * 4, stream);

    k_detect<<<1, 64, 0, stream>>>(ei, flag);
    k_packall<<<(200704 + 255) / 256, 256, 0, stream>>>(
        Wq, Wk, Wv, Wsk, W1, W2, We, wqp, wkp, wvp, wskp, w1p, w2p, wep);
    k_hist<<<(EE + 255) / 256, 256, 0, stream>>>(ei, flag, deg);
    k_proj<<<(NN + 31) / 32, 256, 0, stream>>>(x, wqp, wkp, wvp, wskp,
                                               bq, bk, bv, bsk, qb, kb, vb, skipb);
    k_scan<<<1, 1024, 0, stream>>>(deg, rowstart);
    k_scatter<<<(EE + 255) / 256, 256, 0, stream>>>(ei, flag, rowstart, cursor, srcs, eids);
    k_attn<<<NN, 128, 0, stream>>>(x, ea, wep, qb, kb, vb, skipb,
                                   rowstart, srcs, eids, ln1g, ln1b, hb);
    k_ffn<<<(NN + 31) / 32, 256, 0, stream>>>(hb, w1p, b1, w2p, b2, ln2g, ln2b, (float*)d_out);
}